// Round 3
// baseline (1887.318 us; speedup 1.0000x reference)
//
#include <hip/hip_runtime.h>
#include <math.h>

#define T_LEN 1024
#define B_SZ  256
#define I_SZ  128
#define H_SZ  64
#define G_SZ  256   // 4*H

typedef float f32x8 __attribute__((ext_vector_type(8)));

__device__ __forceinline__ float fast_sigmoid(float x) {
    float e = __expf(-x);
    return __builtin_amdgcn_rcpf(1.0f + e);
}
__device__ __forceinline__ float fast_tanh(float x) {
    float e = __expf(-2.0f * fabsf(x));
    float r = (1.0f - e) * __builtin_amdgcn_rcpf(1.0f + e);
    return copysignf(r, x);
}

// Load 8 floats into an f32x8 SSA value and PIN it: the empty asm makes the
// value opaque (non-rematerializable), forcing the RA to keep it in VGPRs
// across the loop instead of re-loading from memory each iteration.
#define LD8PIN(V, P)                                                        \
    {   float4 t0_ = *reinterpret_cast<const float4*>(P);                   \
        float4 t1_ = *reinterpret_cast<const float4*>((P) + 4);             \
        V = (f32x8){t0_.x, t0_.y, t0_.z, t0_.w, t1_.x, t1_.y, t1_.z, t1_.w};\
        asm volatile("" : "+v"(V)); }

// acc += dot(x[OFF..OFF+7], V) — x loads are block-uniform -> s_load, and the
// scalar operand folds directly into v_fma (1 SGPR source allowed).
#define XDOT8(V, XP, OFF)                                                   \
    {   float4 xa_ = *reinterpret_cast<const float4*>((XP) + (OFF));        \
        float4 xb_ = *reinterpret_cast<const float4*>((XP) + (OFF) + 4);    \
        a0 = fmaf(xa_.x, V[0], a0); a1 = fmaf(xa_.y, V[1], a1);             \
        a2 = fmaf(xa_.z, V[2], a2); a3 = fmaf(xa_.w, V[3], a3);             \
        a0 = fmaf(xb_.x, V[4], a0); a1 = fmaf(xb_.y, V[5], a1);             \
        a2 = fmaf(xb_.z, V[6], a2); a3 = fmaf(xb_.w, V[7], a3); }

// acc += dot(hs4[2Q..2Q+1] (LDS broadcast b128), V)
#define HDOT8(V, Q)                                                         \
    {   float4 ha_ = hs4[2*(Q)];  float4 hb_ = hs4[2*(Q) + 1];              \
        a0 = fmaf(ha_.x, V[0], a0); a1 = fmaf(ha_.y, V[1], a1);             \
        a2 = fmaf(ha_.z, V[2], a2); a3 = fmaf(ha_.w, V[3], a3);             \
        a0 = fmaf(hb_.x, V[4], a0); a1 = fmaf(hb_.y, V[5], a1);             \
        a2 = fmaf(hb_.z, V[6], a2); a3 = fmaf(hb_.w, V[7], a3); }

// ---------------------------------------------------------------------------
// Fused forward LSTM scan. One block per batch element, 256 threads, thread j
// owns gate row j. Weights pinned in 24 f32x8 register values (192 VGPRs).
// x_t read via uniform scalar loads (SGPR operands); only h goes through LDS.
// ---------------------------------------------------------------------------
__global__ __launch_bounds__(256, 1) __attribute__((amdgpu_waves_per_eu(1)))
void lstm_fwd_scan(
    const float* __restrict__ x,      // [T,B,I]
    const float* __restrict__ W_ih,   // [256,128]
    const float* __restrict__ W_hh,   // [256,64]
    const float* __restrict__ bias,   // [256]
    float* __restrict__ h_out)        // [B,64]
{
    const int b = blockIdx.x;
    const int j = threadIdx.x;

    __shared__ float4 hs4[H_SZ / 4];      // h (broadcast-read)
    __shared__ float  gs[G_SZ];           // gate activations

    // ---- weights -> pinned register values
    const float* wr = W_ih + j * I_SZ;
    f32x8 w0, w1, w2, w3, w4, w5, w6, w7, w8, w9, wa, wb, wc, wd, we, wf;
    LD8PIN(w0, wr +   0) LD8PIN(w1, wr +   8) LD8PIN(w2, wr +  16) LD8PIN(w3, wr +  24)
    LD8PIN(w4, wr +  32) LD8PIN(w5, wr +  40) LD8PIN(w6, wr +  48) LD8PIN(w7, wr +  56)
    LD8PIN(w8, wr +  64) LD8PIN(w9, wr +  72) LD8PIN(wa, wr +  80) LD8PIN(wb, wr +  88)
    LD8PIN(wc, wr +  96) LD8PIN(wd, wr + 104) LD8PIN(we, wr + 112) LD8PIN(wf, wr + 120)
    const float* ur = W_hh + j * H_SZ;
    f32x8 u0, u1, u2, u3, u4, u5, u6, u7;
    LD8PIN(u0, ur +   0) LD8PIN(u1, ur +   8) LD8PIN(u2, ur +  16) LD8PIN(u3, ur +  24)
    LD8PIN(u4, ur +  32) LD8PIN(u5, ur +  40) LD8PIN(u6, ur +  48) LD8PIN(u7, ur +  56)
    const float bj = bias[j];

    float c = 0.0f;
    if (j < H_SZ) reinterpret_cast<float*>(hs4)[j] = 0.0f;
    __syncthreads();

    const float* xp = x + (size_t)b * I_SZ;   // block-uniform pointer
    const int gate = j >> 6;                  // wave-uniform (64-lane waves)

    for (int t = 0; t < T_LEN; ++t) {
        float a0 = bj, a1 = 0.0f, a2 = 0.0f, a3 = 0.0f;

        // x-dot: 128 FMAs with SGPR x-operands (also hides h-LDS latency)
        XDOT8(w0, xp,   0) XDOT8(w1, xp,   8) XDOT8(w2, xp,  16) XDOT8(w3, xp,  24)
        XDOT8(w4, xp,  32) XDOT8(w5, xp,  40) XDOT8(w6, xp,  48) XDOT8(w7, xp,  56)
        XDOT8(w8, xp,  64) XDOT8(w9, xp,  72) XDOT8(wa, xp,  80) XDOT8(wb, xp,  88)
        XDOT8(wc, xp,  96) XDOT8(wd, xp, 104) XDOT8(we, xp, 112) XDOT8(wf, xp, 120)

        // h-dot: 16 broadcast ds_read_b128 + 64 FMAs
        HDOT8(u0, 0) HDOT8(u1, 1) HDOT8(u2, 2) HDOT8(u3, 3)
        HDOT8(u4, 4) HDOT8(u5, 5) HDOT8(u6, 6) HDOT8(u7, 7)

        const float acc = (a0 + a1) + (a2 + a3);
        gs[j] = (gate == 2) ? fast_tanh(acc) : fast_sigmoid(acc);
        __syncthreads();                       // gs ready

        if (j < H_SZ) {
            const float ig = gs[j];
            const float fg = gs[H_SZ + j];
            const float gg = gs[2 * H_SZ + j];
            const float og = gs[3 * H_SZ + j];
            c = fg * c + ig * gg;
            reinterpret_cast<float*>(hs4)[j] = og * fast_tanh(c);
        }
        __syncthreads();                       // hs ready for next step
        xp += B_SZ * I_SZ;
    }

    if (j < H_SZ) h_out[b * H_SZ + j] = reinterpret_cast<float*>(hs4)[j];
}

// ---------------------------------------------------------------------------
// Reverse single cell (zero init state; W_hh_r drops out) + MLP head.
// ---------------------------------------------------------------------------
__global__ __launch_bounds__(256, 1) void lstm_tail(
    const float* __restrict__ x_last,  // [B,I]
    const float* __restrict__ W_ih_r,  // [256,128]
    const float* __restrict__ b_r,     // [256]
    const float* __restrict__ h_fwd,   // [B,64]
    const float* __restrict__ fc1_w,   // [64,128]
    const float* __restrict__ fc1_b,   // [64]
    const float* __restrict__ fc2_w,   // [32,64]
    const float* __restrict__ fc2_b,   // [32]
    const float* __restrict__ fc3_w,   // [10,32]
    const float* __restrict__ fc3_b,   // [10]
    float* __restrict__ out)           // [B,10]
{
    const int b = blockIdx.x;
    const int j = threadIdx.x;

    __shared__ float xs[I_SZ];
    __shared__ float gs[G_SZ];
    __shared__ float hc[2 * H_SZ];
    __shared__ float h1[64];
    __shared__ float h2[32];

    if (j < I_SZ) xs[j] = x_last[(size_t)b * I_SZ + j];
    if (j < H_SZ) hc[j] = h_fwd[b * H_SZ + j];
    __syncthreads();

    float a0 = b_r[j], a1 = 0.0f, a2 = 0.0f, a3 = 0.0f;
    const float* wrow = W_ih_r + j * I_SZ;
#pragma unroll
    for (int k = 0; k < I_SZ; k += 4) {
        float4 wv = *reinterpret_cast<const float4*>(wrow + k);
        a0 = fmaf(xs[k + 0], wv.x, a0);
        a1 = fmaf(xs[k + 1], wv.y, a1);
        a2 = fmaf(xs[k + 2], wv.z, a2);
        a3 = fmaf(xs[k + 3], wv.w, a3);
    }
    const float acc = (a0 + a1) + (a2 + a3);
    const int gate = j >> 6;
    gs[j] = (gate == 2) ? tanhf(acc) : 1.0f / (1.0f + expf(-acc));
    __syncthreads();

    if (j < H_SZ) {
        const float cc = gs[j] * gs[2 * H_SZ + j];     // i*g (c0 = 0)
        hc[H_SZ + j] = gs[3 * H_SZ + j] * tanhf(cc);
    }
    __syncthreads();

    if (j < 64) {
        float s0 = fc1_b[j], s1 = 0.0f, s2 = 0.0f, s3 = 0.0f;
        const float* w = fc1_w + j * 128;
#pragma unroll
        for (int k = 0; k < 128; k += 4) {
            float4 wv = *reinterpret_cast<const float4*>(w + k);
            s0 = fmaf(hc[k + 0], wv.x, s0);
            s1 = fmaf(hc[k + 1], wv.y, s1);
            s2 = fmaf(hc[k + 2], wv.z, s2);
            s3 = fmaf(hc[k + 3], wv.w, s3);
        }
        h1[j] = fmaxf((s0 + s1) + (s2 + s3), 0.0f);
    }
    __syncthreads();

    if (j < 32) {
        float s0 = fc2_b[j], s1 = 0.0f, s2 = 0.0f, s3 = 0.0f;
        const float* w = fc2_w + j * 64;
#pragma unroll
        for (int k = 0; k < 64; k += 4) {
            float4 wv = *reinterpret_cast<const float4*>(w + k);
            s0 = fmaf(h1[k + 0], wv.x, s0);
            s1 = fmaf(h1[k + 1], wv.y, s1);
            s2 = fmaf(h1[k + 2], wv.z, s2);
            s3 = fmaf(h1[k + 3], wv.w, s3);
        }
        h2[j] = fmaxf((s0 + s1) + (s2 + s3), 0.0f);
    }
    __syncthreads();

    if (j < 10) {
        float s = fc3_b[j];
#pragma unroll
        for (int k = 0; k < 32; ++k) s = fmaf(h2[k], fc3_w[j * 32 + k], s);
        out[b * 10 + j] = s;
    }
}

extern "C" void kernel_launch(void* const* d_in, const int* in_sizes, int n_in,
                              void* d_out, int out_size, void* d_ws, size_t ws_size,
                              hipStream_t stream) {
    const float* x      = (const float*)d_in[0];
    const float* W_ih_f = (const float*)d_in[1];
    const float* W_hh_f = (const float*)d_in[2];
    const float* b_f    = (const float*)d_in[3];
    const float* W_ih_r = (const float*)d_in[4];
    // d_in[5] = W_hh_r : unused (zero initial state in reverse single step)
    const float* b_r    = (const float*)d_in[6];
    const float* fc1_w  = (const float*)d_in[7];
    const float* fc1_b  = (const float*)d_in[8];
    const float* fc2_w  = (const float*)d_in[9];
    const float* fc2_b  = (const float*)d_in[10];
    const float* fc3_w  = (const float*)d_in[11];
    const float* fc3_b  = (const float*)d_in[12];

    float* out   = (float*)d_out;
    float* h_fwd = (float*)d_ws;                  // [B,64] scratch

    const float* x_last = x + (size_t)(T_LEN - 1) * B_SZ * I_SZ;

    hipLaunchKernelGGL(lstm_fwd_scan, dim3(B_SZ), dim3(256), 0, stream,
                       x, W_ih_f, W_hh_f, b_f, h_fwd);
    hipLaunchKernelGGL(lstm_tail, dim3(B_SZ), dim3(256), 0, stream,
                       x_last, W_ih_r, b_r, h_fwd,
                       fc1_w, fc1_b, fc2_w, fc2_b, fc3_w, fc3_b, out);
}

// Round 4
// 761.107 us; speedup vs baseline: 2.4797x; 2.4797x over previous
//
#include <hip/hip_runtime.h>
#include <math.h>

#define T_LEN 1024
#define B_SZ  256
#define I_SZ  128
#define H_SZ  64
#define G_SZ  256   // 4*H

typedef float f32x8 __attribute__((ext_vector_type(8)));

__device__ __forceinline__ float fast_sigmoid(float x) {
    float e = __expf(-x);
    return __builtin_amdgcn_rcpf(1.0f + e);
}
__device__ __forceinline__ float fast_tanh(float x) {
    float e = __expf(-2.0f * fabsf(x));
    float r = (1.0f - e) * __builtin_amdgcn_rcpf(1.0f + e);
    return copysignf(r, x);
}

// Load 8 floats into an f32x8 SSA value; asm makes it non-rematerializable.
// (48 floats/thread fits the 128-VGPR/4-wave budget, so no spill pressure.)
#define LD8PIN(V, P)                                                        \
    {   float4 t0_ = *reinterpret_cast<const float4*>(P);                   \
        float4 t1_ = *reinterpret_cast<const float4*>((P) + 4);             \
        V = (f32x8){t0_.x, t0_.y, t0_.z, t0_.w, t1_.x, t1_.y, t1_.z, t1_.w};\
        asm volatile("" : "+v"(V)); }

// acc(4 chains) += dot(V[0..7], {F4A,F4B})
#define DOT2(V, F4A, F4B)                                                   \
    {   const float4 fa_ = (F4A), fb_ = (F4B);                              \
        a0 = fmaf(fa_.x, V[0], a0); a1 = fmaf(fa_.y, V[1], a1);             \
        a2 = fmaf(fa_.z, V[2], a2); a3 = fmaf(fa_.w, V[3], a3);             \
        a0 = fmaf(fb_.x, V[4], a0); a1 = fmaf(fb_.y, V[5], a1);             \
        a2 = fmaf(fb_.z, V[6], a2); a3 = fmaf(fb_.w, V[7], a3); }

// ---------------------------------------------------------------------------
// Forward LSTM scan. One block per batch element, 1024 threads (16 waves).
// Thread (j = tid>>2, q = tid&3) computes a quarter of gate row j's dot
// product with 48 register-resident weights; quad-reduced via 2x shfl_xor.
// x_t staged in LDS with +8-word/segment swizzle so the four q-groups read
// disjoint banks; h broadcast from LDS (2-way aliasing = free).
// ---------------------------------------------------------------------------
__global__ __launch_bounds__(1024, 4) void lstm_fwd_scan(
    const float* __restrict__ x,      // [T,B,I]
    const float* __restrict__ W_ih,   // [256,128]
    const float* __restrict__ W_hh,   // [256,64]
    const float* __restrict__ bias,   // [256]
    float* __restrict__ h_out)        // [B,64]
{
    const int b   = blockIdx.x;
    const int tid = threadIdx.x;
    const int j   = tid >> 2;        // gate row 0..255
    const int q   = tid & 3;         // quarter 0..3

    // logical x index k lives at word (k&31) + 40*(k>>5)  (8-word pad/segment)
    __shared__ __align__(16) float xs[2][160];
    __shared__ __align__(16) float hs[H_SZ];
    __shared__ float gs[G_SZ];

    // ---- per-thread weight quarter -> registers
    const float* wr = W_ih + j * I_SZ + q * 32;
    f32x8 w0, w1, w2, w3;
    LD8PIN(w0, wr +  0) LD8PIN(w1, wr +  8) LD8PIN(w2, wr + 16) LD8PIN(w3, wr + 24)
    const float* ur = W_hh + j * H_SZ + q * 16;
    f32x8 u0, u1;
    LD8PIN(u0, ur + 0) LD8PIN(u1, ur + 8)
    const float bj = (q == 0) ? bias[j] : 0.0f;

    float c = 0.0f;                                   // cell state (tid<64)
    if (tid < H_SZ) hs[tid] = 0.0f;
    if (tid < I_SZ) xs[0][(tid & 31) + 40 * (tid >> 5)] = x[(size_t)b * I_SZ + tid];
    __syncthreads();

    const float* xnp = x + (size_t)B_SZ * I_SZ + (size_t)b * I_SZ + tid;
    const int gate = tid >> 8;                        // wave-uniform: i,f,g,o

    for (int t = 0; t < T_LEN; ++t) {
        const int  cur = t & 1;
        const bool pf  = (tid < I_SZ) & (t < T_LEN - 1);
        float xnext = 0.0f;
        if (pf) xnext = *xnp;                         // issue global load early

        // quarter dot: 32 x-FMAs + 16 h-FMAs, 4 independent chains
        float a0 = bj, a1 = 0.0f, a2 = 0.0f, a3 = 0.0f;
        const float4* xc = reinterpret_cast<const float4*>(&xs[cur][40 * q]);
        DOT2(w0, xc[0], xc[1]) DOT2(w1, xc[2], xc[3])
        DOT2(w2, xc[4], xc[5]) DOT2(w3, xc[6], xc[7])
        const float4* hp = reinterpret_cast<const float4*>(&hs[16 * q]);
        DOT2(u0, hp[0], hp[1]) DOT2(u1, hp[2], hp[3])

        float acc = (a0 + a1) + (a2 + a3);
        acc += __shfl_xor(acc, 1, 64);                // quad butterfly reduce
        acc += __shfl_xor(acc, 2, 64);

        const float a = (gate == 2) ? fast_tanh(acc) : fast_sigmoid(acc);
        if (q == 0) gs[j] = a;
        __syncthreads();                              // gs ready

        // prefetched x -> other buffer (vmcnt wait hidden under the dot)
        if (pf) xs[cur ^ 1][(tid & 31) + 40 * (tid >> 5)] = xnext;

        if (tid < H_SZ) {                             // cell update (wave 0)
            const float ig = gs[tid];
            const float fg = gs[H_SZ + tid];
            const float gg = gs[2 * H_SZ + tid];
            const float og = gs[3 * H_SZ + tid];
            c = fg * c + ig * gg;
            hs[tid] = og * fast_tanh(c);
        }
        __syncthreads();                              // hs ready
        xnp += B_SZ * I_SZ;
    }

    if (tid < H_SZ) h_out[b * H_SZ + tid] = hs[tid];
}

// ---------------------------------------------------------------------------
// Reverse single cell (zero init state; W_hh_r drops out) + MLP head.
// ---------------------------------------------------------------------------
__global__ __launch_bounds__(256, 1) void lstm_tail(
    const float* __restrict__ x_last,  // [B,I]
    const float* __restrict__ W_ih_r,  // [256,128]
    const float* __restrict__ b_r,     // [256]
    const float* __restrict__ h_fwd,   // [B,64]
    const float* __restrict__ fc1_w,   // [64,128]
    const float* __restrict__ fc1_b,   // [64]
    const float* __restrict__ fc2_w,   // [32,64]
    const float* __restrict__ fc2_b,   // [32]
    const float* __restrict__ fc3_w,   // [10,32]
    const float* __restrict__ fc3_b,   // [10]
    float* __restrict__ out)           // [B,10]
{
    const int b = blockIdx.x;
    const int j = threadIdx.x;

    __shared__ float xs[I_SZ];
    __shared__ float gs[G_SZ];
    __shared__ float hc[2 * H_SZ];
    __shared__ float h1[64];
    __shared__ float h2[32];

    if (j < I_SZ) xs[j] = x_last[(size_t)b * I_SZ + j];
    if (j < H_SZ) hc[j] = h_fwd[b * H_SZ + j];
    __syncthreads();

    float a0 = b_r[j], a1 = 0.0f, a2 = 0.0f, a3 = 0.0f;
    const float* wrow = W_ih_r + j * I_SZ;
#pragma unroll
    for (int k = 0; k < I_SZ; k += 4) {
        float4 wv = *reinterpret_cast<const float4*>(wrow + k);
        a0 = fmaf(xs[k + 0], wv.x, a0);
        a1 = fmaf(xs[k + 1], wv.y, a1);
        a2 = fmaf(xs[k + 2], wv.z, a2);
        a3 = fmaf(xs[k + 3], wv.w, a3);
    }
    const float acc = (a0 + a1) + (a2 + a3);
    const int gate = j >> 6;
    gs[j] = (gate == 2) ? tanhf(acc) : 1.0f / (1.0f + expf(-acc));
    __syncthreads();

    if (j < H_SZ) {
        const float cc = gs[j] * gs[2 * H_SZ + j];     // i*g (c0 = 0)
        hc[H_SZ + j] = gs[3 * H_SZ + j] * tanhf(cc);
    }
    __syncthreads();

    if (j < 64) {
        float s0 = fc1_b[j], s1 = 0.0f, s2 = 0.0f, s3 = 0.0f;
        const float* w = fc1_w + j * 128;
#pragma unroll
        for (int k = 0; k < 128; k += 4) {
            float4 wv = *reinterpret_cast<const float4*>(w + k);
            s0 = fmaf(hc[k + 0], wv.x, s0);
            s1 = fmaf(hc[k + 1], wv.y, s1);
            s2 = fmaf(hc[k + 2], wv.z, s2);
            s3 = fmaf(hc[k + 3], wv.w, s3);
        }
        h1[j] = fmaxf((s0 + s1) + (s2 + s3), 0.0f);
    }
    __syncthreads();

    if (j < 32) {
        float s0 = fc2_b[j], s1 = 0.0f, s2 = 0.0f, s3 = 0.0f;
        const float* w = fc2_w + j * 64;
#pragma unroll
        for (int k = 0; k < 64; k += 4) {
            float4 wv = *reinterpret_cast<const float4*>(w + k);
            s0 = fmaf(h1[k + 0], wv.x, s0);
            s1 = fmaf(h1[k + 1], wv.y, s1);
            s2 = fmaf(h1[k + 2], wv.z, s2);
            s3 = fmaf(h1[k + 3], wv.w, s3);
        }
        h2[j] = fmaxf((s0 + s1) + (s2 + s3), 0.0f);
    }
    __syncthreads();

    if (j < 10) {
        float s = fc3_b[j];
#pragma unroll
        for (int k = 0; k < 32; ++k) s = fmaf(h2[k], fc3_w[j * 32 + k], s);
        out[b * 10 + j] = s;
    }
}

extern "C" void kernel_launch(void* const* d_in, const int* in_sizes, int n_in,
                              void* d_out, int out_size, void* d_ws, size_t ws_size,
                              hipStream_t stream) {
    const float* x      = (const float*)d_in[0];
    const float* W_ih_f = (const float*)d_in[1];
    const float* W_hh_f = (const float*)d_in[2];
    const float* b_f    = (const float*)d_in[3];
    const float* W_ih_r = (const float*)d_in[4];
    // d_in[5] = W_hh_r : unused (zero initial state in reverse single step)
    const float* b_r    = (const float*)d_in[6];
    const float* fc1_w  = (const float*)d_in[7];
    const float* fc1_b  = (const float*)d_in[8];
    const float* fc2_w  = (const float*)d_in[9];
    const float* fc2_b  = (const float*)d_in[10];
    const float* fc3_w  = (const float*)d_in[11];
    const float* fc3_b  = (const float*)d_in[12];

    float* out   = (float*)d_out;
    float* h_fwd = (float*)d_ws;                  // [B,64] scratch

    const float* x_last = x + (size_t)(T_LEN - 1) * B_SZ * I_SZ;

    hipLaunchKernelGGL(lstm_fwd_scan, dim3(B_SZ), dim3(1024), 0, stream,
                       x, W_ih_f, W_hh_f, b_f, h_fwd);
    hipLaunchKernelGGL(lstm_tail, dim3(B_SZ), dim3(256), 0, stream,
                       x_last, W_ih_r, b_r, h_fwd,
                       fc1_w, fc1_b, fc2_w, fc2_b, fc3_w, fc3_b, out);
}